// Round 8
// baseline (202.149 us; speedup 1.0000x reference)
//
#include <hip/hip_runtime.h>
#include <stdint.h>

typedef float f32x4 __attribute__((ext_vector_type(4)));
typedef __bf16 bf16x8 __attribute__((ext_vector_type(8)));
typedef unsigned short u16;

__device__ __forceinline__ void gload_lds16(const void* g, void* l) {
  __builtin_amdgcn_global_load_lds(
      (__attribute__((address_space(1))) void*)(uintptr_t)(g),
      (__attribute__((address_space(3))) void*)(uint32_t)(uintptr_t)(l),
      16, 0, 0);
}

__device__ __forceinline__ u16 f2bf(float x) {
  __bf16 h = (__bf16)x;
  return *(u16*)&h;
}

__device__ __forceinline__ void barrier_raw() {
  __builtin_amdgcn_sched_barrier(0);
  __builtin_amdgcn_s_barrier();
  __builtin_amdgcn_sched_barrier(0);
}

#define VMCNT(n) asm volatile("s_waitcnt vmcnt(" #n ")" ::: "memory")
#define LGKM0()                                    \
  do {                                             \
    asm volatile("s_waitcnt lgkmcnt(0)" ::: "memory"); \
    __builtin_amdgcn_sched_barrier(0);             \
  } while (0)

// ---------------- fused cast f32 -> bf16 for all 7 arrays ----------------
__global__ __launch_bounds__(256) void cast_all(
    const float* __restrict__ q, const float* __restrict__ k,
    const float* __restrict__ v, const float* __restrict__ wq,
    const float* __restrict__ wk, const float* __restrict__ wv,
    const float* __restrict__ wo, u16* __restrict__ out) {
  const int g = blockIdx.x;
  const float* in;
  int s;
  if (g < 8192) { in = q; s = 0; }
  else if (g < 14336) { in = k; s = 8192; }
  else if (g < 20480) { in = v; s = 14336; }
  else if (g < 21504) { in = wq; s = 20480; }
  else if (g < 22272) { in = wk; s = 21504; }
  else if (g < 23040) { in = wv; s = 22272; }
  else { in = wo; s = 23040; }
  const int li = (g - s) * 256 + threadIdx.x;
  float4 x = *((const float4*)in + li);
  unsigned lo = (unsigned)f2bf(x.x) | ((unsigned)f2bf(x.y) << 16);
  unsigned hi = (unsigned)f2bf(x.z) | ((unsigned)f2bf(x.w) << 16);
  ((uint2*)out)[(size_t)g * 256 + threadIdx.x] = make_uint2(lo, hi);
}

// ---------------- merged Q/K/V projection GEMM ----------------
// BM=256 x BN=128, 4 waves (128x64/wave). 3-buffer LDS + counted vmcnt (DMA
// slack = 1 full phase) + REGISTER double-buffered fragments: per K-step,
// ds_reads for tile t+1 issue right after the barrier and complete UNDER the
// MFMA cluster for tile t (frags already in regs). Hazard: buf X's reads
// (step X-1) are >=2 barriers before its restage (step X+1). Roles
// interleaved (y%3) to mix K=1024/768 blocks in the dispatch tail.
__global__ __launch_bounds__(256, 2) void proj_kernel(
    const u16* __restrict__ qb, const u16* __restrict__ kb,
    const u16* __restrict__ vb, const u16* __restrict__ wqb,
    const u16* __restrict__ wkb, const u16* __restrict__ wvb,
    const float* __restrict__ bq, const float* __restrict__ bk,
    const float* __restrict__ bv, u16* __restrict__ qpb,
    u16* __restrict__ kpb, u16* __restrict__ vtb) {
  __shared__ __align__(16) u16 As[3][256 * 32];
  __shared__ __align__(16) u16 Bs[3][128 * 32];
  const int tid = threadIdx.x;
  const int role = blockIdx.y % 3;
  const int m0 = blockIdx.x * 256, n0 = (blockIdx.y / 3) * 128;
  const int K = (role == 0) ? 1024 : 768;
  const u16* A = (role == 0) ? qb : ((role == 1) ? kb : vb);
  const u16* Bt = (role == 0) ? wqb : ((role == 1) ? wkb : wvb);
  const float* bias = (role == 0) ? bq : ((role == 1) ? bk : bv);
  const int lane = tid & 63, w = tid >> 6;
  const int wr = w >> 1, wc = w & 1;
  const int l16 = lane & 15, lk = lane >> 4;
  const int nk = K >> 5;  // 32 or 24, always even
  const int srow = tid >> 2;
  const int sw = (tid & 3) ^ ((tid >> 3) & 3);
  const int e2 = (l16 >> 1) & 3;

  const u16* Ap = A + (size_t)(m0 + srow) * K + sw * 8;
  const u16* Bp = Bt + (size_t)(n0 + srow) * K + sw * 8;

  f32x4 acc[8][4] = {};
  bf16x8 aA[8], bA[4], aB[8], bB[4];

  auto stage = [&](int t, int ktile) {
    const int ko = ktile << 5;
#pragma unroll
    for (int l = 0; l < 4; ++l)
      gload_lds16(Ap + (size_t)l * 64 * K + ko, As[t] + tid * 8 + l * 2048);
#pragma unroll
    for (int l = 0; l < 2; ++l)
      gload_lds16(Bp + (size_t)l * 64 * K + ko, Bs[t] + tid * 8 + l * 2048);
  };
  auto rd = [&](bf16x8 (&a)[8], bf16x8 (&b)[4], int c) {
#pragma unroll
    for (int i = 0; i < 8; ++i)
      a[i] = *(const bf16x8*)(As[c] + (wr * 128 + i * 16 + l16) * 32 + (lk ^ e2) * 8);
#pragma unroll
    for (int j = 0; j < 4; ++j)
      b[j] = *(const bf16x8*)(Bs[c] + (wc * 64 + j * 16 + l16) * 32 + (lk ^ e2) * 8);
  };
  auto mm = [&](bf16x8 (&a)[8], bf16x8 (&b)[4]) {
    __builtin_amdgcn_s_setprio(1);
#pragma unroll
    for (int i = 0; i < 8; ++i)
#pragma unroll
      for (int j = 0; j < 4; ++j)
        acc[i][j] = __builtin_amdgcn_mfma_f32_16x16x32_bf16(a[i], b[j], acc[i][j], 0, 0, 0);
    __builtin_amdgcn_s_setprio(0);
  };

  // prologue: tiles 0,1 staged; frags(0) -> set A
  stage(0, 0);
  stage(1, 1);
  VMCNT(6);
  barrier_raw();
  rd(aA, bA, 0);
  LGKM0();

  int cur = 0;
  for (int kt = 0; kt < nk; kt += 2) {
    const int c1 = (cur == 2) ? 0 : cur + 1;
    const int c2 = (c1 == 2) ? 0 : c1 + 1;
    // even: stage kt+2 -> c2 | read kt+1 (c1) under MFMA(kt, set A)
    if (kt + 2 < nk) { stage(c2, kt + 2); VMCNT(6); }
    else { VMCNT(0); }
    barrier_raw();
    rd(aB, bB, c1);
    mm(aA, bA);
    LGKM0();
    barrier_raw();
    // odd: stage kt+3 -> cur | read kt+2 (c2) under MFMA(kt+1, set B)
    if (kt + 3 < nk) { stage(cur, kt + 3); VMCNT(6); }
    else { VMCNT(0); }
    barrier_raw();
    if (kt + 2 < nk) rd(aA, bA, c2);
    mm(aB, bB);
    LGKM0();
    barrier_raw();
    cur = c2;
  }

#pragma unroll
  for (int i = 0; i < 8; ++i) {
    const int mrow = m0 + wr * 128 + i * 16 + lk * 4;
#pragma unroll
    for (int j = 0; j < 4; ++j) {
      const int col = n0 + wc * 64 + j * 16 + l16;
      const float bval = bias[col];
      if (role == 0) {
#pragma unroll
        for (int r = 0; r < 4; ++r)
          qpb[(size_t)(mrow + r) * 1024 + col] = f2bf(acc[i][j][r] + bval);
      } else if (role == 1) {
#pragma unroll
        for (int r = 0; r < 4; ++r)
          kpb[(size_t)(mrow + r) * 1024 + col] = f2bf(acc[i][j][r] + bval);
      } else {  // vt[b][h][d][l], rows r are 4 consecutive l
        const int bb = mrow >> 10, l = mrow & 1023;
        const int hh = col >> 6, dd = col & 63;
        u16 u0 = f2bf(acc[i][j][0] + bval);
        u16 u1 = f2bf(acc[i][j][1] + bval);
        u16 u2 = f2bf(acc[i][j][2] + bval);
        u16 u3 = f2bf(acc[i][j][3] + bval);
        uint2 pkt = make_uint2((unsigned)u0 | ((unsigned)u1 << 16),
                               (unsigned)u2 | ((unsigned)u3 << 16));
        *(uint2*)(vtb + ((size_t)((bb * 16 + hh) * 64 + dd) << 10) + l) = pkt;
      }
    }
  }
}

// ---------------- fused masked flash attention ----------------
// grid = (qt=16, h=16, b=8), block = 256 (4 waves x 16 q-rows).
__global__ __launch_bounds__(256) void attn_kernel(
    const u16* __restrict__ qp, const u16* __restrict__ kp,
    const u16* __restrict__ vt, const int* __restrict__ mask,
    u16* __restrict__ out) {
  __shared__ __align__(16) u16 KV[2][2][64 * 64];  // [buf][0=K,1=V]
  __shared__ __align__(16) u16 Ps[4][16 * 64];     // XOR-swizzled (8-u16 chunks)
  const int tid = threadIdx.x;
  const int qt = blockIdx.x, h = blockIdx.y, b = blockIdx.z;
  const int lane = tid & 63, w = tid >> 6;
  const int l16 = lane & 15, lk = lane >> 4;
  const int srow = tid >> 3, schunk = tid & 7;
  const int sw = schunk ^ (srow & 7);  // pre-swizzled source chunk

  // per-wave prefix-mask popcount -> len (no LDS, no cross-wave comm)
  int cnt = 0;
  {
    const int4* mp = (const int4*)(mask + (b << 10));
#pragma unroll
    for (int i = 0; i < 4; ++i) {
      const int4 mv = mp[lane * 4 + i];
      cnt += (mv.x ? 1 : 0) + (mv.y ? 1 : 0) + (mv.z ? 1 : 0) + (mv.w ? 1 : 0);
    }
#pragma unroll
    for (int off = 1; off < 64; off <<= 1) cnt += __shfl_xor(cnt, off);
  }
  const int ntile = (cnt + 63) >> 6;
  const int rem = cnt & 63;

  // stage Q into KV[1][0] (temporary), K0/V0 into KV[0]
#pragma unroll
  for (int p = 0; p < 2; ++p) {
    gload_lds16(qp + (((size_t)(b * 1024 + qt * 64 + p * 32 + srow)) << 10) + h * 64 + sw * 8,
                KV[1][0] + tid * 8 + p * 2048);
    gload_lds16(kp + (((size_t)(b * 1024 + p * 32 + srow)) << 10) + h * 64 + sw * 8,
                KV[0][0] + tid * 8 + p * 2048);
    gload_lds16(vt + (((size_t)((b * 16 + h) * 64 + p * 32 + srow)) << 10) + sw * 8,
                KV[0][1] + tid * 8 + p * 2048);
  }
  __syncthreads();
  const int qrow = w * 16 + l16, qs = qrow & 7;
  bf16x8 aq0 = *(const bf16x8*)(KV[1][0] + qrow * 64 + (lk ^ qs) * 8);
  bf16x8 aq1 = *(const bf16x8*)(KV[1][0] + qrow * 64 + ((lk + 4) ^ qs) * 8);
  __syncthreads();  // all waves done with Q region before buf1 prefetch

  const float SC2 = 0.18033688011112042f;  // 0.125 * log2(e)
  float lsumq = 0.f;                       // row-sum for q = l16 (per lane)
  f32x4 oacc[4] = {};
  const int e7 = l16 & 7;

  int cur = 0;
  for (int kt = 0; kt < ntile; ++kt) {
    // issue next-tile prefetch FIRST (stays in flight across compute)
    if (kt + 1 < ntile) {
#pragma unroll
      for (int p = 0; p < 2; ++p) {
        gload_lds16(kp + (((size_t)(b * 1024 + (kt + 1) * 64 + p * 32 + srow)) << 10) + h * 64 + sw * 8,
                    KV[cur ^ 1][0] + tid * 8 + p * 2048);
        gload_lds16(vt + (((size_t)((b * 16 + h) * 64 + p * 32 + srow)) << 10) + (kt + 1) * 64 + sw * 8,
                    KV[cur ^ 1][1] + tid * 8 + p * 2048);
      }
    }
    const u16* Kb = KV[cur][0];
    const u16* Vb = KV[cur][1];

    // QK^T, swapped operands: lane holds S[key=nf*16+lk*4+r][q=l16]
    f32x4 sfr[4] = {};
    __builtin_amdgcn_s_setprio(1);
#pragma unroll
    for (int nf = 0; nf < 4; ++nf) {
      const int krow = nf * 16 + l16;
      bf16x8 bk0 = *(const bf16x8*)(Kb + krow * 64 + (lk ^ e7) * 8);
      bf16x8 bk1 = *(const bf16x8*)(Kb + krow * 64 + ((lk + 4) ^ e7) * 8);
      sfr[nf] = __builtin_amdgcn_mfma_f32_16x16x32_bf16(bk0, aq0, sfr[nf], 0, 0, 0);
      sfr[nf] = __builtin_amdgcn_mfma_f32_16x16x32_bf16(bk1, aq1, sfr[nf], 0, 0, 0);
    }
    __builtin_amdgcn_s_setprio(0);

    // fixed-shift softmax; only the single partial tile needs mask math
    const bool partial = (kt == ntile - 1) && (rem != 0);
    u16* Pw = &Ps[w][0];
#pragma unroll
    for (int nf = 0; nf < 4; ++nf) {
      float pv0 = __builtin_amdgcn_exp2f(sfr[nf][0] * SC2);
      float pv1 = __builtin_amdgcn_exp2f(sfr[nf][1] * SC2);
      float pv2 = __builtin_amdgcn_exp2f(sfr[nf][2] * SC2);
      float pv3 = __builtin_amdgcn_exp2f(sfr[nf][3] * SC2);
      if (partial) {
        const int k0 = nf * 16 + lk * 4;
        pv0 = (k0 + 0 < rem) ? pv0 : 0.f;
        pv1 = (k0 + 1 < rem) ? pv1 : 0.f;
        pv2 = (k0 + 2 < rem) ? pv2 : 0.f;
        pv3 = (k0 + 3 < rem) ? pv3 : 0.f;
      }
      lsumq += (pv0 + pv1) + (pv2 + pv3);
      unsigned lo = (unsigned)f2bf(pv0) | ((unsigned)f2bf(pv1) << 16);
      unsigned hi = (unsigned)f2bf(pv2) | ((unsigned)f2bf(pv3) << 16);
      // chunk (nf*2 + lk>>1) XOR (l16&7), sub-slot lk&1
      *(uint2*)(Pw + l16 * 64 + (((nf * 2 + (lk >> 1)) ^ e7) * 8 + (lk & 1) * 4)) =
          make_uint2(lo, hi);
    }

    bf16x8 ap0 = *(const bf16x8*)(Pw + l16 * 64 + ((lk ^ e7) * 8));
    bf16x8 ap1 = *(const bf16x8*)(Pw + l16 * 64 + (((4 + lk) ^ e7) * 8));
    __builtin_amdgcn_s_setprio(1);
#pragma unroll
    for (int nf = 0; nf < 4; ++nf) {
      const int vrow = nf * 16 + l16;
      bf16x8 bv0 = *(const bf16x8*)(Vb + vrow * 64 + (lk ^ e7) * 8);
      bf16x8 bv1 = *(const bf16x8*)(Vb + vrow * 64 + ((lk + 4) ^ e7) * 8);
      oacc[nf] = __builtin_amdgcn_mfma_f32_16x16x32_bf16(ap0, bv0, oacc[nf], 0, 0, 0);
      oacc[nf] = __builtin_amdgcn_mfma_f32_16x16x32_bf16(ap1, bv1, oacc[nf], 0, 0, 0);
    }
    __builtin_amdgcn_s_setprio(0);

    __syncthreads();  // drains prefetch (vmcnt0) + all waves done with KV[cur]
    cur ^= 1;
  }

  // reduce row-sum across the 4 lanes sharing l16, redistribute to out layout
  lsumq += __shfl_xor(lsumq, 16);
  lsumq += __shfl_xor(lsumq, 32);
  float rinv[4];
#pragma unroll
  for (int r = 0; r < 4; ++r) rinv[r] = 1.0f / __shfl(lsumq, lk * 4 + r);

#pragma unroll
  for (int nf = 0; nf < 4; ++nf)
#pragma unroll
    for (int r = 0; r < 4; ++r) {
      const int tok = b * 1024 + qt * 64 + w * 16 + lk * 4 + r;
      const int col = h * 64 + nf * 16 + l16;
      out[((size_t)tok << 10) + col] = f2bf(oacc[nf][r] * rinv[r]);
    }
}

// ---------------- O-projection GEMM + bias + f32 residual ----------------
// Same 3-buffer + register-dbuf-frag pipeline; 48KB LDS -> 3 blocks/CU.
__global__ __launch_bounds__(256, 3) void gemm_o(
    const u16* __restrict__ A, const u16* __restrict__ Bt,
    const float* __restrict__ bias, float* __restrict__ Cf,
    const float* __restrict__ res) {
  __shared__ __align__(16) u16 As[3][128 * 32];
  __shared__ __align__(16) u16 Bs[3][128 * 32];
  const int K = 1024, N = 1024, nk = 32;
  const int tid = threadIdx.x;
  const int m0 = blockIdx.x * 128, n0 = blockIdx.y * 128;
  const int lane = tid & 63, w = tid >> 6;
  const int wr = w >> 1, wc = w & 1;
  const int l16 = lane & 15, lk = lane >> 4;
  const int srow = tid >> 2;
  const int sw = (tid & 3) ^ ((tid >> 3) & 3);
  const int e2 = (l16 >> 1) & 3;

  const u16* Ap = A + (size_t)(m0 + srow) * K + sw * 8;
  const u16* Bp = Bt + (size_t)(n0 + srow) * K + sw * 8;

  f32x4 acc[4][4] = {};
  bf16x8 aA[4], bA[4], aB[4], bB[4];

  auto stage = [&](int t, int ktile) {
    const int ko = ktile << 5;
#pragma unroll
    for (int p = 0; p < 2; ++p) {
      gload_lds16(Ap + (size_t)p * 64 * K + ko, As[t] + tid * 8 + p * 2048);
      gload_lds16(Bp + (size_t)p * 64 * K + ko, Bs[t] + tid * 8 + p * 2048);
    }
  };
  auto rd = [&](bf16x8 (&a)[4], bf16x8 (&b)[4], int c) {
#pragma unroll
    for (int i = 0; i < 4; ++i)
      a[i] = *(const bf16x8*)(As[c] + (wr * 64 + i * 16 + l16) * 32 + (lk ^ e2) * 8);
#pragma unroll
    for (int j = 0; j < 4; ++j)
      b[j] = *(const bf16x8*)(Bs[c] + (wc * 64 + j * 16 + l16) * 32 + (lk ^ e2) * 8);
  };
  auto mm = [&](bf16x8 (&a)[4], bf16x8 (&b)[4]) {
    __builtin_amdgcn_s_setprio(1);
#pragma unroll
    for (int i = 0; i < 4; ++i)
#pragma unroll
      for (int j = 0; j < 4; ++j)
        acc[i][j] = __builtin_amdgcn_mfma_f32_16x16x32_bf16(a[i], b[j], acc[i][j], 0, 0, 0);
    __builtin_amdgcn_s_setprio(0);
  };

  stage(0, 0);
  stage(1, 1);
  VMCNT(4);
  barrier_raw();
  rd(aA, bA, 0);
  LGKM0();

  int cur = 0;
  for (int kt = 0; kt < nk; kt += 2) {
    const int c1 = (cur == 2) ? 0 : cur + 1;
    const int c2 = (c1 == 2) ? 0 : c1 + 1;
    if (kt + 2 < nk) { stage(c2, kt + 2); VMCNT(4); }
    else { VMCNT(0); }
    barrier_raw();
    rd(aB, bB, c1);
    mm(aA, bA);
    LGKM0();
    barrier_raw();
    if (kt + 3 < nk) { stage(cur, kt + 3); VMCNT(4); }
    else { VMCNT(0); }
    barrier_raw();
    if (kt + 2 < nk) rd(aA, bA, c2);
    mm(aB, bB);
    LGKM0();
    barrier_raw();
    cur = c2;
  }

#pragma unroll
  for (int i = 0; i < 4; ++i) {
    const int mrow = m0 + wr * 64 + i * 16 + lk * 4;
#pragma unroll
    for (int j = 0; j < 4; ++j) {
      const int col = n0 + wc * 64 + j * 16 + l16;
      const float bval = bias[col];
#pragma unroll
      for (int r = 0; r < 4; ++r) {
        const size_t idx = (size_t)(mrow + r) * N + col;
        Cf[idx] = acc[i][j][r] + bval + res[idx];
      }
    }
  }
}

// ---------------- in-place LayerNorm over rows of 1024 f32 ----------------
__global__ __launch_bounds__(256) void ln_kernel(float* __restrict__ y,
                                                 const float* __restrict__ gamma,
                                                 const float* __restrict__ beta) {
  __shared__ float ssum[4], ssq[4];
  const int tid = threadIdx.x;
  float* yr = y + ((size_t)blockIdx.x << 10);
  float4 v = *((const float4*)yr + tid);
  float s = v.x + v.y + v.z + v.w;
  float q2 = v.x * v.x + v.y * v.y + v.z * v.z + v.w * v.w;
#pragma unroll
  for (int off = 1; off < 64; off <<= 1) {
    s += __shfl_xor(s, off);
    q2 += __shfl_xor(q2, off);
  }
  if ((tid & 63) == 0) { ssum[tid >> 6] = s; ssq[tid >> 6] = q2; }
  __syncthreads();
  s = ssum[0] + ssum[1] + ssum[2] + ssum[3];
  q2 = ssq[0] + ssq[1] + ssq[2] + ssq[3];
  const float mu = s * (1.0f / 1024.0f);
  const float rstd = rsqrtf(q2 * (1.0f / 1024.0f) - mu * mu + 1e-5f);
  float4 g = *((const float4*)gamma + tid);
  float4 be = *((const float4*)beta + tid);
  float4 o;
  o.x = (v.x - mu) * rstd * g.x + be.x;
  o.y = (v.y - mu) * rstd * g.y + be.y;
  o.z = (v.z - mu) * rstd * g.z + be.z;
  o.w = (v.w - mu) * rstd * g.w + be.w;
  *((float4*)yr + tid) = o;
}

extern "C" void kernel_launch(void* const* d_in, const int* in_sizes, int n_in,
                              void* d_out, int out_size, void* d_ws, size_t ws_size,
                              hipStream_t stream) {
  (void)in_sizes; (void)n_in; (void)out_size; (void)ws_size;
  const float* q = (const float*)d_in[0];
  const float* k = (const float*)d_in[1];
  const float* v = (const float*)d_in[2];
  const int* msk = (const int*)d_in[3];
  const float* Wq = (const float*)d_in[4];
  const float* bq = (const float*)d_in[5];
  const float* Wk = (const float*)d_in[6];
  const float* bk = (const float*)d_in[7];
  const float* Wv = (const float*)d_in[8];
  const float* bv = (const float*)d_in[9];
  const float* Wo = (const float*)d_in[10];
  const float* bo = (const float*)d_in[11];
  const float* gamma = (const float*)d_in[12];
  const float* beta = (const float*)d_in[13];
  float* out = (float*)d_out;

  char* p = (char*)d_ws;
  auto take = [&p](size_t bytes) {
    char* r = p;
    p += (bytes + 255) & ~(size_t)255;
    return r;
  };
  u16* qb = (u16*)take(8192ull * 1024 * 2);
  u16* kb = (u16*)take(8192ull * 768 * 2);
  u16* vb = (u16*)take(8192ull * 768 * 2);
  u16* wqb = (u16*)take(1024ull * 1024 * 2);
  u16* wkb = (u16*)take(1024ull * 768 * 2);
  u16* wvb = (u16*)take(1024ull * 768 * 2);
  u16* wob = (u16*)take(1024ull * 1024 * 2);
  u16* qpb = (u16*)take(8192ull * 1024 * 2);
  u16* kpb = (u16*)take(8192ull * 1024 * 2);
  u16* vtb = (u16*)take(8192ull * 1024 * 2);  // [B][H][64][1024]
  u16* atb = (u16*)take(8192ull * 1024 * 2);

  cast_all<<<dim3(24064), 256, 0, stream>>>(q, k, v, Wq, Wk, Wv, Wo, qb);

  proj_kernel<<<dim3(32, 24), 256, 0, stream>>>(qb, kb, vb, wqb, wkb, wvb,
                                                bq, bk, bv, qpb, kpb, vtb);

  attn_kernel<<<dim3(16, 16, 8), 256, 0, stream>>>(qpb, kpb, vtb, msk, atb);

  gemm_o<<<dim3(64, 8), 256, 0, stream>>>(atb, wob, bo, out, q);

  ln_kernel<<<dim3(8192), 256, 0, stream>>>(out, gamma, beta);
}

// Round 9
// 198.965 us; speedup vs baseline: 1.0160x; 1.0160x over previous
//
#include <hip/hip_runtime.h>
#include <stdint.h>

typedef float f32x4 __attribute__((ext_vector_type(4)));
typedef __bf16 bf16x8 __attribute__((ext_vector_type(8)));
typedef unsigned short u16;

__device__ __forceinline__ void gload_lds16(const void* g, void* l) {
  __builtin_amdgcn_global_load_lds(
      (__attribute__((address_space(1))) void*)(uintptr_t)(g),
      (__attribute__((address_space(3))) void*)(uint32_t)(uintptr_t)(l),
      16, 0, 0);
}

__device__ __forceinline__ u16 f2bf(float x) {
  __bf16 h = (__bf16)x;
  return *(u16*)&h;
}

__device__ __forceinline__ void barrier_raw() {
  __builtin_amdgcn_sched_barrier(0);
  __builtin_amdgcn_s_barrier();
  __builtin_amdgcn_sched_barrier(0);
}

#define VMCNT(n) asm volatile("s_waitcnt vmcnt(" #n ")" ::: "memory")
#define LGKM0()                                    \
  do {                                             \
    asm volatile("s_waitcnt lgkmcnt(0)" ::: "memory"); \
    __builtin_amdgcn_sched_barrier(0);             \
  } while (0)

// ---------------- fused cast f32 -> bf16 for all 7 arrays ----------------
__global__ __launch_bounds__(256) void cast_all(
    const float* __restrict__ q, const float* __restrict__ k,
    const float* __restrict__ v, const float* __restrict__ wq,
    const float* __restrict__ wk, const float* __restrict__ wv,
    const float* __restrict__ wo, u16* __restrict__ out) {
  const int g = blockIdx.x;
  const float* in;
  int s;
  if (g < 8192) { in = q; s = 0; }
  else if (g < 14336) { in = k; s = 8192; }
  else if (g < 20480) { in = v; s = 14336; }
  else if (g < 21504) { in = wq; s = 20480; }
  else if (g < 22272) { in = wk; s = 21504; }
  else if (g < 23040) { in = wv; s = 22272; }
  else { in = wo; s = 23040; }
  const int li = (g - s) * 256 + threadIdx.x;
  float4 x = *((const float4*)in + li);
  unsigned lo = (unsigned)f2bf(x.x) | ((unsigned)f2bf(x.y) << 16);
  unsigned hi = (unsigned)f2bf(x.z) | ((unsigned)f2bf(x.w) << 16);
  ((uint2*)out)[(size_t)g * 256 + threadIdx.x] = make_uint2(lo, hi);
}

// ---------------- merged Q/K/V projection GEMM ----------------
// BM=256 x BN=128, 4 waves (128x64/wave). 3-buffer LDS + counted vmcnt (DMA
// slack = 1 full phase) + register double-buffered fragments (ds_reads for
// tile t+1 complete UNDER tile t's MFMA cluster). Role grouping y>>3 is
// REQUIRED: consecutive blocks share one A matrix -> panels stay L2-resident
// (R8's y%3 interleave: FETCH +57%, DMA latency -> HBM-miss, -30% perf).
__global__ __launch_bounds__(256, 2) void proj_kernel(
    const u16* __restrict__ qb, const u16* __restrict__ kb,
    const u16* __restrict__ vb, const u16* __restrict__ wqb,
    const u16* __restrict__ wkb, const u16* __restrict__ wvb,
    const float* __restrict__ bq, const float* __restrict__ bk,
    const float* __restrict__ bv, u16* __restrict__ qpb,
    u16* __restrict__ kpb, u16* __restrict__ vtb) {
  __shared__ __align__(16) u16 As[3][256 * 32];
  __shared__ __align__(16) u16 Bs[3][128 * 32];
  const int tid = threadIdx.x;
  const int role = blockIdx.y >> 3;
  const int m0 = blockIdx.x * 256, n0 = (blockIdx.y & 7) * 128;
  const int K = (role == 0) ? 1024 : 768;
  const u16* A = (role == 0) ? qb : ((role == 1) ? kb : vb);
  const u16* Bt = (role == 0) ? wqb : ((role == 1) ? wkb : wvb);
  const float* bias = (role == 0) ? bq : ((role == 1) ? bk : bv);
  const int lane = tid & 63, w = tid >> 6;
  const int wr = w >> 1, wc = w & 1;
  const int l16 = lane & 15, lk = lane >> 4;
  const int nk = K >> 5;  // 32 or 24, always even
  const int srow = tid >> 2;
  const int sw = (tid & 3) ^ ((tid >> 3) & 3);
  const int e2 = (l16 >> 1) & 3;

  const u16* Ap = A + (size_t)(m0 + srow) * K + sw * 8;
  const u16* Bp = Bt + (size_t)(n0 + srow) * K + sw * 8;

  f32x4 acc[8][4] = {};
  bf16x8 aA[8], bA[4], aB[8], bB[4];

  auto stage = [&](int t, int ktile) {
    const int ko = ktile << 5;
#pragma unroll
    for (int l = 0; l < 4; ++l)
      gload_lds16(Ap + (size_t)l * 64 * K + ko, As[t] + tid * 8 + l * 2048);
#pragma unroll
    for (int l = 0; l < 2; ++l)
      gload_lds16(Bp + (size_t)l * 64 * K + ko, Bs[t] + tid * 8 + l * 2048);
  };
  auto rd = [&](bf16x8 (&a)[8], bf16x8 (&b)[4], int c) {
#pragma unroll
    for (int i = 0; i < 8; ++i)
      a[i] = *(const bf16x8*)(As[c] + (wr * 128 + i * 16 + l16) * 32 + (lk ^ e2) * 8);
#pragma unroll
    for (int j = 0; j < 4; ++j)
      b[j] = *(const bf16x8*)(Bs[c] + (wc * 64 + j * 16 + l16) * 32 + (lk ^ e2) * 8);
  };
  auto mm = [&](bf16x8 (&a)[8], bf16x8 (&b)[4]) {
    __builtin_amdgcn_s_setprio(1);
#pragma unroll
    for (int i = 0; i < 8; ++i)
#pragma unroll
      for (int j = 0; j < 4; ++j)
        acc[i][j] = __builtin_amdgcn_mfma_f32_16x16x32_bf16(a[i], b[j], acc[i][j], 0, 0, 0);
    __builtin_amdgcn_s_setprio(0);
  };

  // prologue: tiles 0,1 staged; frags(0) -> set A
  stage(0, 0);
  stage(1, 1);
  VMCNT(6);
  barrier_raw();
  rd(aA, bA, 0);
  LGKM0();

  int cur = 0;
  for (int kt = 0; kt < nk; kt += 2) {
    const int c1 = (cur == 2) ? 0 : cur + 1;
    const int c2 = (c1 == 2) ? 0 : c1 + 1;
    // even: stage kt+2 -> c2 | read kt+1 (c1) under MFMA(kt, set A)
    if (kt + 2 < nk) { stage(c2, kt + 2); VMCNT(6); }
    else { VMCNT(0); }
    barrier_raw();
    rd(aB, bB, c1);
    mm(aA, bA);
    LGKM0();
    barrier_raw();
    // odd: stage kt+3 -> cur | read kt+2 (c2) under MFMA(kt+1, set B)
    if (kt + 3 < nk) { stage(cur, kt + 3); VMCNT(6); }
    else { VMCNT(0); }
    barrier_raw();
    if (kt + 2 < nk) rd(aA, bA, c2);
    mm(aB, bB);
    LGKM0();
    barrier_raw();
    cur = c2;
  }

#pragma unroll
  for (int i = 0; i < 8; ++i) {
    const int mrow = m0 + wr * 128 + i * 16 + lk * 4;
#pragma unroll
    for (int j = 0; j < 4; ++j) {
      const int col = n0 + wc * 64 + j * 16 + l16;
      const float bval = bias[col];
      if (role == 0) {
#pragma unroll
        for (int r = 0; r < 4; ++r)
          qpb[(size_t)(mrow + r) * 1024 + col] = f2bf(acc[i][j][r] + bval);
      } else if (role == 1) {
#pragma unroll
        for (int r = 0; r < 4; ++r)
          kpb[(size_t)(mrow + r) * 1024 + col] = f2bf(acc[i][j][r] + bval);
      } else {  // vt[b][h][d][l], rows r are 4 consecutive l
        const int bb = mrow >> 10, l = mrow & 1023;
        const int hh = col >> 6, dd = col & 63;
        u16 u0 = f2bf(acc[i][j][0] + bval);
        u16 u1 = f2bf(acc[i][j][1] + bval);
        u16 u2 = f2bf(acc[i][j][2] + bval);
        u16 u3 = f2bf(acc[i][j][3] + bval);
        uint2 pkt = make_uint2((unsigned)u0 | ((unsigned)u1 << 16),
                               (unsigned)u2 | ((unsigned)u3 << 16));
        *(uint2*)(vtb + ((size_t)((bb * 16 + hh) * 64 + dd) << 10) + l) = pkt;
      }
    }
  }
}

// ---------------- fused masked flash attention ----------------
// grid = (qt=16, h=16, b=8), block = 256 (4 waves x 16 q-rows).
__global__ __launch_bounds__(256) void attn_kernel(
    const u16* __restrict__ qp, const u16* __restrict__ kp,
    const u16* __restrict__ vt, const int* __restrict__ mask,
    u16* __restrict__ out) {
  __shared__ __align__(16) u16 KV[2][2][64 * 64];  // [buf][0=K,1=V]
  __shared__ __align__(16) u16 Ps[4][16 * 64];     // XOR-swizzled (8-u16 chunks)
  const int tid = threadIdx.x;
  const int qt = blockIdx.x, h = blockIdx.y, b = blockIdx.z;
  const int lane = tid & 63, w = tid >> 6;
  const int l16 = lane & 15, lk = lane >> 4;
  const int srow = tid >> 3, schunk = tid & 7;
  const int sw = schunk ^ (srow & 7);  // pre-swizzled source chunk

  // per-wave prefix-mask popcount -> len (no LDS, no cross-wave comm)
  int cnt = 0;
  {
    const int4* mp = (const int4*)(mask + (b << 10));
#pragma unroll
    for (int i = 0; i < 4; ++i) {
      const int4 mv = mp[lane * 4 + i];
      cnt += (mv.x ? 1 : 0) + (mv.y ? 1 : 0) + (mv.z ? 1 : 0) + (mv.w ? 1 : 0);
    }
#pragma unroll
    for (int off = 1; off < 64; off <<= 1) cnt += __shfl_xor(cnt, off);
  }
  const int ntile = (cnt + 63) >> 6;
  const int rem = cnt & 63;

  // stage Q into KV[1][0] (temporary), K0/V0 into KV[0]
#pragma unroll
  for (int p = 0; p < 2; ++p) {
    gload_lds16(qp + (((size_t)(b * 1024 + qt * 64 + p * 32 + srow)) << 10) + h * 64 + sw * 8,
                KV[1][0] + tid * 8 + p * 2048);
    gload_lds16(kp + (((size_t)(b * 1024 + p * 32 + srow)) << 10) + h * 64 + sw * 8,
                KV[0][0] + tid * 8 + p * 2048);
    gload_lds16(vt + (((size_t)((b * 16 + h) * 64 + p * 32 + srow)) << 10) + sw * 8,
                KV[0][1] + tid * 8 + p * 2048);
  }
  __syncthreads();
  const int qrow = w * 16 + l16, qs = qrow & 7;
  bf16x8 aq0 = *(const bf16x8*)(KV[1][0] + qrow * 64 + (lk ^ qs) * 8);
  bf16x8 aq1 = *(const bf16x8*)(KV[1][0] + qrow * 64 + ((lk + 4) ^ qs) * 8);
  __syncthreads();  // all waves done with Q region before buf1 prefetch

  const float SC2 = 0.18033688011112042f;  // 0.125 * log2(e)
  float lsumq = 0.f;                       // row-sum for q = l16 (per lane)
  f32x4 oacc[4] = {};
  const int e7 = l16 & 7;

  int cur = 0;
  for (int kt = 0; kt < ntile; ++kt) {
    // issue next-tile prefetch FIRST (stays in flight across compute)
    if (kt + 1 < ntile) {
#pragma unroll
      for (int p = 0; p < 2; ++p) {
        gload_lds16(kp + (((size_t)(b * 1024 + (kt + 1) * 64 + p * 32 + srow)) << 10) + h * 64 + sw * 8,
                    KV[cur ^ 1][0] + tid * 8 + p * 2048);
        gload_lds16(vt + (((size_t)((b * 16 + h) * 64 + p * 32 + srow)) << 10) + (kt + 1) * 64 + sw * 8,
                    KV[cur ^ 1][1] + tid * 8 + p * 2048);
      }
    }
    const u16* Kb = KV[cur][0];
    const u16* Vb = KV[cur][1];

    // QK^T, swapped operands: lane holds S[key=nf*16+lk*4+r][q=l16]
    f32x4 sfr[4] = {};
    __builtin_amdgcn_s_setprio(1);
#pragma unroll
    for (int nf = 0; nf < 4; ++nf) {
      const int krow = nf * 16 + l16;
      bf16x8 bk0 = *(const bf16x8*)(Kb + krow * 64 + (lk ^ e7) * 8);
      bf16x8 bk1 = *(const bf16x8*)(Kb + krow * 64 + ((lk + 4) ^ e7) * 8);
      sfr[nf] = __builtin_amdgcn_mfma_f32_16x16x32_bf16(bk0, aq0, sfr[nf], 0, 0, 0);
      sfr[nf] = __builtin_amdgcn_mfma_f32_16x16x32_bf16(bk1, aq1, sfr[nf], 0, 0, 0);
    }
    __builtin_amdgcn_s_setprio(0);

    // fixed-shift softmax; only the single partial tile needs mask math
    const bool partial = (kt == ntile - 1) && (rem != 0);
    u16* Pw = &Ps[w][0];
#pragma unroll
    for (int nf = 0; nf < 4; ++nf) {
      float pv0 = __builtin_amdgcn_exp2f(sfr[nf][0] * SC2);
      float pv1 = __builtin_amdgcn_exp2f(sfr[nf][1] * SC2);
      float pv2 = __builtin_amdgcn_exp2f(sfr[nf][2] * SC2);
      float pv3 = __builtin_amdgcn_exp2f(sfr[nf][3] * SC2);
      if (partial) {
        const int k0 = nf * 16 + lk * 4;
        pv0 = (k0 + 0 < rem) ? pv0 : 0.f;
        pv1 = (k0 + 1 < rem) ? pv1 : 0.f;
        pv2 = (k0 + 2 < rem) ? pv2 : 0.f;
        pv3 = (k0 + 3 < rem) ? pv3 : 0.f;
      }
      lsumq += (pv0 + pv1) + (pv2 + pv3);
      unsigned lo = (unsigned)f2bf(pv0) | ((unsigned)f2bf(pv1) << 16);
      unsigned hi = (unsigned)f2bf(pv2) | ((unsigned)f2bf(pv3) << 16);
      // chunk (nf*2 + lk>>1) XOR (l16&7), sub-slot lk&1
      *(uint2*)(Pw + l16 * 64 + (((nf * 2 + (lk >> 1)) ^ e7) * 8 + (lk & 1) * 4)) =
          make_uint2(lo, hi);
    }

    bf16x8 ap0 = *(const bf16x8*)(Pw + l16 * 64 + ((lk ^ e7) * 8));
    bf16x8 ap1 = *(const bf16x8*)(Pw + l16 * 64 + (((4 + lk) ^ e7) * 8));
    __builtin_amdgcn_s_setprio(1);
#pragma unroll
    for (int nf = 0; nf < 4; ++nf) {
      const int vrow = nf * 16 + l16;
      bf16x8 bv0 = *(const bf16x8*)(Vb + vrow * 64 + (lk ^ e7) * 8);
      bf16x8 bv1 = *(const bf16x8*)(Vb + vrow * 64 + ((lk + 4) ^ e7) * 8);
      oacc[nf] = __builtin_amdgcn_mfma_f32_16x16x32_bf16(ap0, bv0, oacc[nf], 0, 0, 0);
      oacc[nf] = __builtin_amdgcn_mfma_f32_16x16x32_bf16(ap1, bv1, oacc[nf], 0, 0, 0);
    }
    __builtin_amdgcn_s_setprio(0);

    __syncthreads();  // drains prefetch (vmcnt0) + all waves done with KV[cur]
    cur ^= 1;
  }

  // reduce row-sum across the 4 lanes sharing l16, redistribute to out layout
  lsumq += __shfl_xor(lsumq, 16);
  lsumq += __shfl_xor(lsumq, 32);
  float rinv[4];
#pragma unroll
  for (int r = 0; r < 4; ++r) rinv[r] = 1.0f / __shfl(lsumq, lk * 4 + r);

#pragma unroll
  for (int nf = 0; nf < 4; ++nf)
#pragma unroll
    for (int r = 0; r < 4; ++r) {
      const int tok = b * 1024 + qt * 64 + w * 16 + lk * 4 + r;
      const int col = h * 64 + nf * 16 + l16;
      out[((size_t)tok << 10) + col] = f2bf(oacc[nf][r] * rinv[r]);
    }
}

// ---------------- O-projection GEMM + bias + f32 residual ----------------
// 3-buffer + register-dbuf-frag pipeline; 48KB LDS -> 3 blocks/CU.
__global__ __launch_bounds__(256, 3) void gemm_o(
    const u16* __restrict__ A, const u16* __restrict__ Bt,
    const float* __restrict__ bias, float* __restrict__ Cf,
    const float* __restrict__ res) {
  __shared__ __align__(16) u16 As[3][128 * 32];
  __shared__ __align__(16) u16 Bs[3][128 * 32];
  const int K = 1024, N = 1024, nk = 32;
  const int tid = threadIdx.x;
  const int m0 = blockIdx.x * 128, n0 = blockIdx.y * 128;
  const int lane = tid & 63, w = tid >> 6;
  const int wr = w >> 1, wc = w & 1;
  const int l16 = lane & 15, lk = lane >> 4;
  const int srow = tid >> 2;
  const int sw = (tid & 3) ^ ((tid >> 3) & 3);
  const int e2 = (l16 >> 1) & 3;

  const u16* Ap = A + (size_t)(m0 + srow) * K + sw * 8;
  const u16* Bp = Bt + (size_t)(n0 + srow) * K + sw * 8;

  f32x4 acc[4][4] = {};
  bf16x8 aA[4], bA[4], aB[4], bB[4];

  auto stage = [&](int t, int ktile) {
    const int ko = ktile << 5;
#pragma unroll
    for (int p = 0; p < 2; ++p) {
      gload_lds16(Ap + (size_t)p * 64 * K + ko, As[t] + tid * 8 + p * 2048);
      gload_lds16(Bp + (size_t)p * 64 * K + ko, Bs[t] + tid * 8 + p * 2048);
    }
  };
  auto rd = [&](bf16x8 (&a)[4], bf16x8 (&b)[4], int c) {
#pragma unroll
    for (int i = 0; i < 4; ++i)
      a[i] = *(const bf16x8*)(As[c] + (wr * 64 + i * 16 + l16) * 32 + (lk ^ e2) * 8);
#pragma unroll
    for (int j = 0; j < 4; ++j)
      b[j] = *(const bf16x8*)(Bs[c] + (wc * 64 + j * 16 + l16) * 32 + (lk ^ e2) * 8);
  };
  auto mm = [&](bf16x8 (&a)[4], bf16x8 (&b)[4]) {
    __builtin_amdgcn_s_setprio(1);
#pragma unroll
    for (int i = 0; i < 4; ++i)
#pragma unroll
      for (int j = 0; j < 4; ++j)
        acc[i][j] = __builtin_amdgcn_mfma_f32_16x16x32_bf16(a[i], b[j], acc[i][j], 0, 0, 0);
    __builtin_amdgcn_s_setprio(0);
  };

  stage(0, 0);
  stage(1, 1);
  VMCNT(4);
  barrier_raw();
  rd(aA, bA, 0);
  LGKM0();

  int cur = 0;
  for (int kt = 0; kt < nk; kt += 2) {
    const int c1 = (cur == 2) ? 0 : cur + 1;
    const int c2 = (c1 == 2) ? 0 : c1 + 1;
    if (kt + 2 < nk) { stage(c2, kt + 2); VMCNT(4); }
    else { VMCNT(0); }
    barrier_raw();
    rd(aB, bB, c1);
    mm(aA, bA);
    LGKM0();
    barrier_raw();
    if (kt + 3 < nk) { stage(cur, kt + 3); VMCNT(4); }
    else { VMCNT(0); }
    barrier_raw();
    if (kt + 2 < nk) rd(aA, bA, c2);
    mm(aB, bB);
    LGKM0();
    barrier_raw();
    cur = c2;
  }

#pragma unroll
  for (int i = 0; i < 4; ++i) {
    const int mrow = m0 + wr * 64 + i * 16 + lk * 4;
#pragma unroll
    for (int j = 0; j < 4; ++j) {
      const int col = n0 + wc * 64 + j * 16 + l16;
      const float bval = bias[col];
#pragma unroll
      for (int r = 0; r < 4; ++r) {
        const size_t idx = (size_t)(mrow + r) * N + col;
        Cf[idx] = acc[i][j][r] + bval + res[idx];
      }
    }
  }
}

// ---------------- in-place LayerNorm over rows of 1024 f32 ----------------
__global__ __launch_bounds__(256) void ln_kernel(float* __restrict__ y,
                                                 const float* __restrict__ gamma,
                                                 const float* __restrict__ beta) {
  __shared__ float ssum[4], ssq[4];
  const int tid = threadIdx.x;
  float* yr = y + ((size_t)blockIdx.x << 10);
  float4 v = *((const float4*)yr + tid);
  float s = v.x + v.y + v.z + v.w;
  float q2 = v.x * v.x + v.y * v.y + v.z * v.z + v.w * v.w;
#pragma unroll
  for (int off = 1; off < 64; off <<= 1) {
    s += __shfl_xor(s, off);
    q2 += __shfl_xor(q2, off);
  }
  if ((tid & 63) == 0) { ssum[tid >> 6] = s; ssq[tid >> 6] = q2; }
  __syncthreads();
  s = ssum[0] + ssum[1] + ssum[2] + ssum[3];
  q2 = ssq[0] + ssq[1] + ssq[2] + ssq[3];
  const float mu = s * (1.0f / 1024.0f);
  const float rstd = rsqrtf(q2 * (1.0f / 1024.0f) - mu * mu + 1e-5f);
  float4 g = *((const float4*)gamma + tid);
  float4 be = *((const float4*)beta + tid);
  float4 o;
  o.x = (v.x - mu) * rstd * g.x + be.x;
  o.y = (v.y - mu) * rstd * g.y + be.y;
  o.z = (v.z - mu) * rstd * g.z + be.z;
  o.w = (v.w - mu) * rstd * g.w + be.w;
  *((float4*)yr + tid) = o;
}

extern "C" void kernel_launch(void* const* d_in, const int* in_sizes, int n_in,
                              void* d_out, int out_size, void* d_ws, size_t ws_size,
                              hipStream_t stream) {
  (void)in_sizes; (void)n_in; (void)out_size; (void)ws_size;
  const float* q = (const float*)d_in[0];
  const float* k = (const float*)d_in[1];
  const float* v = (const float*)d_in[2];
  const int* msk = (const int*)d_in[3];
  const float* Wq = (const float*)d_in[4];
  const float* bq = (const float*)d_in[5];
  const float* Wk = (const float*)d_in[6];
  const float* bk = (const float*)d_in[7];
  const float* Wv = (const float*)d_in[8];
  const float* bv = (const float*)d_in[9];
  const float* Wo = (const float*)d_in[10];
  const float* bo = (const float*)d_in[11];
  const float* gamma = (const float*)d_in[12];
  const float* beta = (const float*)d_in[13];
  float* out = (float*)d_out;

  char* p = (char*)d_ws;
  auto take = [&p](size_t bytes) {
    char* r = p;
    p += (bytes + 255) & ~(size_t)255;
    return r;
  };
  u16* qb = (u16*)take(8192ull * 1024 * 2);
  u16* kb = (u16*)take(8192ull * 768 * 2);
  u16* vb = (u16*)take(8192ull * 768 * 2);
  u16* wqb = (u16*)take(1024ull * 1024 * 2);
  u16* wkb = (u16*)take(1024ull * 768 * 2);
  u16* wvb = (u16*)take(1024ull * 768 * 2);
  u16* wob = (u16*)take(1024ull * 1024 * 2);
  u16* qpb = (u16*)take(8192ull * 1024 * 2);
  u16* kpb = (u16*)take(8192ull * 1024 * 2);
  u16* vtb = (u16*)take(8192ull * 1024 * 2);  // [B][H][64][1024]
  u16* atb = (u16*)take(8192ull * 1024 * 2);

  cast_all<<<dim3(24064), 256, 0, stream>>>(q, k, v, Wq, Wk, Wv, Wo, qb);

  proj_kernel<<<dim3(32, 24), 256, 0, stream>>>(qb, kb, vb, wqb, wkb, wvb,
                                                bq, bk, bv, qpb, kpb, vtb);

  attn_kernel<<<dim3(16, 16, 8), 256, 0, stream>>>(qpb, kpb, vtb, msk, atb);

  gemm_o<<<dim3(64, 8), 256, 0, stream>>>(atb, wob, bo, out, q);

  ln_kernel<<<dim3(8192), 256, 0, stream>>>(out, gamma, beta);
}

// Round 10
// 175.253 us; speedup vs baseline: 1.1535x; 1.1353x over previous
//
#include <hip/hip_runtime.h>
#include <stdint.h>

typedef float f32x4 __attribute__((ext_vector_type(4)));
typedef __bf16 bf16x8 __attribute__((ext_vector_type(8)));
typedef unsigned short u16;

__device__ __forceinline__ void gload_lds16(const void* g, void* l) {
  __builtin_amdgcn_global_load_lds(
      (__attribute__((address_space(1))) void*)(uintptr_t)(g),
      (__attribute__((address_space(3))) void*)(uint32_t)(uintptr_t)(l),
      16, 0, 0);
}

__device__ __forceinline__ u16 f2bf(float x) {
  __bf16 h = (__bf16)x;
  return *(u16*)&h;
}

__device__ __forceinline__ void barrier_raw() {
  __builtin_amdgcn_sched_barrier(0);
  __builtin_amdgcn_s_barrier();
  __builtin_amdgcn_sched_barrier(0);
}

#define VMCNT(n) asm volatile("s_waitcnt vmcnt(" #n ")" ::: "memory")
#define LGKM0()                                    \
  do {                                             \
    asm volatile("s_waitcnt lgkmcnt(0)" ::: "memory"); \
    __builtin_amdgcn_sched_barrier(0);             \
  } while (0)

// ---------------- fused cast f32 -> bf16 for all 7 arrays ----------------
__global__ __launch_bounds__(256) void cast_all(
    const float* __restrict__ q, const float* __restrict__ k,
    const float* __restrict__ v, const float* __restrict__ wq,
    const float* __restrict__ wk, const float* __restrict__ wv,
    const float* __restrict__ wo, u16* __restrict__ out) {
  const int g = blockIdx.x;
  const float* in;
  int s;
  if (g < 8192) { in = q; s = 0; }
  else if (g < 14336) { in = k; s = 8192; }
  else if (g < 20480) { in = v; s = 14336; }
  else if (g < 21504) { in = wq; s = 20480; }
  else if (g < 22272) { in = wk; s = 21504; }
  else if (g < 23040) { in = wv; s = 22272; }
  else { in = wo; s = 23040; }
  const int li = (g - s) * 256 + threadIdx.x;
  float4 x = *((const float4*)in + li);
  unsigned lo = (unsigned)f2bf(x.x) | ((unsigned)f2bf(x.y) << 16);
  unsigned hi = (unsigned)f2bf(x.z) | ((unsigned)f2bf(x.w) << 16);
  ((uint2*)out)[(size_t)g * 256 + threadIdx.x] = make_uint2(lo, hi);
}

// ---------------- merged Q/K/V projection GEMM (R7 structure) ----------------
// BM=256 x BN=128, 4 waves (128x64/wave): 32 MFMA per 12 ds_read_b128.
// 3-buffer LDS, counted vmcnt with 2-phase DMA slack (stage kt+2, wait tile
// kt: vmcnt 12/6/0). NO register-dbuf of fragments and NO lgkm fences: the
// compiler's fine-grained lgkmcnt interleave of ds_read with MFMA beats the
// pinned variant (R9: 88us vs this structure's 66us). Role grouping y>>3
// keeps A panels XCD-L2-resident (R8's y%3: FETCH +57%, -30% perf).
__global__ __launch_bounds__(256, 2) void proj_kernel(
    const u16* __restrict__ qb, const u16* __restrict__ kb,
    const u16* __restrict__ vb, const u16* __restrict__ wqb,
    const u16* __restrict__ wkb, const u16* __restrict__ wvb,
    const float* __restrict__ bq, const float* __restrict__ bk,
    const float* __restrict__ bv, u16* __restrict__ qpb,
    u16* __restrict__ kpb, u16* __restrict__ vtb) {
  __shared__ __align__(16) u16 As[3][256 * 32];
  __shared__ __align__(16) u16 Bs[3][128 * 32];
  const int tid = threadIdx.x;
  const int role = blockIdx.y >> 3;
  const int m0 = blockIdx.x * 256, n0 = (blockIdx.y & 7) * 128;
  const int K = (role == 0) ? 1024 : 768;
  const u16* A = (role == 0) ? qb : ((role == 1) ? kb : vb);
  const u16* Bt = (role == 0) ? wqb : ((role == 1) ? wkb : wvb);
  const float* bias = (role == 0) ? bq : ((role == 1) ? bk : bv);
  const int lane = tid & 63, w = tid >> 6;
  const int wr = w >> 1, wc = w & 1;
  const int l16 = lane & 15, lk = lane >> 4;
  const int nk = K >> 5;
  const int srow = tid >> 2;
  const int sw = (tid & 3) ^ ((tid >> 3) & 3);

  const u16* Ap = A + (size_t)(m0 + srow) * K + sw * 8;
  const u16* Bp = Bt + (size_t)(n0 + srow) * K + sw * 8;

  f32x4 acc[8][4] = {};

  auto stage = [&](int t, int ko) {
#pragma unroll
    for (int l = 0; l < 4; ++l)
      gload_lds16(Ap + (size_t)l * 64 * K + ko, As[t] + tid * 8 + l * 2048);
#pragma unroll
    for (int l = 0; l < 2; ++l)
      gload_lds16(Bp + (size_t)l * 64 * K + ko, Bs[t] + tid * 8 + l * 2048);
  };

  // prologue: tiles 0,1 in flight (12 loads)
  stage(0, 0);
  stage(1, 32);

  const int e2 = (l16 >> 1) & 3;  // read-side swizzle
  int cur = 0;
  for (int kt = 0; kt < nk; ++kt) {
    const int stg = (cur >= 1) ? cur - 1 : 2;  // (cur+2)%3
    if (kt + 2 < nk) {
      stage(stg, (kt + 2) << 5);
      asm volatile("s_waitcnt vmcnt(12)" ::: "memory");
    } else if (kt + 1 < nk) {
      asm volatile("s_waitcnt vmcnt(6)" ::: "memory");
    } else {
      asm volatile("s_waitcnt vmcnt(0)" ::: "memory");
    }
    barrier_raw();  // all waves' buf[cur] DMA writes landed

    bf16x8 a[8], b[4];
#pragma unroll
    for (int i = 0; i < 8; ++i)
      a[i] = *(const bf16x8*)(As[cur] + (wr * 128 + i * 16 + l16) * 32 + (lk ^ e2) * 8);
#pragma unroll
    for (int j = 0; j < 4; ++j)
      b[j] = *(const bf16x8*)(Bs[cur] + (wc * 64 + j * 16 + l16) * 32 + (lk ^ e2) * 8);
    __builtin_amdgcn_s_setprio(1);
#pragma unroll
    for (int i = 0; i < 8; ++i)
#pragma unroll
      for (int j = 0; j < 4; ++j)
        acc[i][j] = __builtin_amdgcn_mfma_f32_16x16x32_bf16(a[i], b[j], acc[i][j], 0, 0, 0);
    __builtin_amdgcn_s_setprio(0);
    barrier_raw();  // all waves done reading buf[cur]
    cur = (cur < 2) ? cur + 1 : 0;
  }

#pragma unroll
  for (int i = 0; i < 8; ++i) {
    const int mrow = m0 + wr * 128 + i * 16 + lk * 4;
#pragma unroll
    for (int j = 0; j < 4; ++j) {
      const int col = n0 + wc * 64 + j * 16 + l16;
      const float bval = bias[col];
      if (role == 0) {
#pragma unroll
        for (int r = 0; r < 4; ++r)
          qpb[(size_t)(mrow + r) * 1024 + col] = f2bf(acc[i][j][r] + bval);
      } else if (role == 1) {
#pragma unroll
        for (int r = 0; r < 4; ++r)
          kpb[(size_t)(mrow + r) * 1024 + col] = f2bf(acc[i][j][r] + bval);
      } else {  // vt[b][h][d][l], rows r are 4 consecutive l
        const int bb = mrow >> 10, l = mrow & 1023;
        const int hh = col >> 6, dd = col & 63;
        u16 u0 = f2bf(acc[i][j][0] + bval);
        u16 u1 = f2bf(acc[i][j][1] + bval);
        u16 u2 = f2bf(acc[i][j][2] + bval);
        u16 u3 = f2bf(acc[i][j][3] + bval);
        uint2 pkt = make_uint2((unsigned)u0 | ((unsigned)u1 << 16),
                               (unsigned)u2 | ((unsigned)u3 << 16));
        *(uint2*)(vtb + ((size_t)((bb * 16 + hh) * 64 + dd) << 10) + l) = pkt;
      }
    }
  }
}

// ---------------- fused masked flash attention ----------------
// grid = 2048 flat, block = 256 (4 waves x 16 q-rows). XCD-locality decode:
// bid = r + 8*q + 128*j  ->  bh = r + 8*j (XCD-determined), qt = q.
// All 16 qt-blocks of one (b,h) share an XCD -> its 256KB K/V panel stays in
// that XCD's L2 (16 bh/XCD x 256KB = 4MB = L2 size); default consecutive-bid
// round-robin fetched each panel on every XCD (attn FETCH 112MB vs ~50 ideal).
__global__ __launch_bounds__(256) void attn_kernel(
    const u16* __restrict__ qp, const u16* __restrict__ kp,
    const u16* __restrict__ vt, const int* __restrict__ mask,
    u16* __restrict__ out) {
  __shared__ __align__(16) u16 KV[2][2][64 * 64];  // [buf][0=K,1=V]
  __shared__ __align__(16) u16 Ps[4][16 * 64];     // XOR-swizzled (8-u16 chunks)
  const int tid = threadIdx.x;
  const int bid = blockIdx.x;
  const int qt = (bid >> 3) & 15;
  const int bh = (bid & 7) + ((bid >> 7) << 3);
  const int b = bh >> 4, h = bh & 15;
  const int lane = tid & 63, w = tid >> 6;
  const int l16 = lane & 15, lk = lane >> 4;
  const int srow = tid >> 3, schunk = tid & 7;
  const int sw = schunk ^ (srow & 7);  // pre-swizzled source chunk

  // per-wave prefix-mask popcount -> len (no LDS, no cross-wave comm)
  int cnt = 0;
  {
    const int4* mp = (const int4*)(mask + (b << 10));
#pragma unroll
    for (int i = 0; i < 4; ++i) {
      const int4 mv = mp[lane * 4 + i];
      cnt += (mv.x ? 1 : 0) + (mv.y ? 1 : 0) + (mv.z ? 1 : 0) + (mv.w ? 1 : 0);
    }
#pragma unroll
    for (int off = 1; off < 64; off <<= 1) cnt += __shfl_xor(cnt, off);
  }
  const int ntile = (cnt + 63) >> 6;
  const int rem = cnt & 63;

  // stage Q into KV[1][0] (temporary), K0/V0 into KV[0]
#pragma unroll
  for (int p = 0; p < 2; ++p) {
    gload_lds16(qp + (((size_t)(b * 1024 + qt * 64 + p * 32 + srow)) << 10) + h * 64 + sw * 8,
                KV[1][0] + tid * 8 + p * 2048);
    gload_lds16(kp + (((size_t)(b * 1024 + p * 32 + srow)) << 10) + h * 64 + sw * 8,
                KV[0][0] + tid * 8 + p * 2048);
    gload_lds16(vt + (((size_t)((b * 16 + h) * 64 + p * 32 + srow)) << 10) + sw * 8,
                KV[0][1] + tid * 8 + p * 2048);
  }
  __syncthreads();
  const int qrow = w * 16 + l16, qs = qrow & 7;
  bf16x8 aq0 = *(const bf16x8*)(KV[1][0] + qrow * 64 + (lk ^ qs) * 8);
  bf16x8 aq1 = *(const bf16x8*)(KV[1][0] + qrow * 64 + ((lk + 4) ^ qs) * 8);
  __syncthreads();  // all waves done with Q region before buf1 prefetch

  const float SC2 = 0.18033688011112042f;  // 0.125 * log2(e)
  float lsumq = 0.f;                       // row-sum for q = l16 (per lane)
  f32x4 oacc[4] = {};
  const int e7 = l16 & 7;

  int cur = 0;
  for (int kt = 0; kt < ntile; ++kt) {
    // issue next-tile prefetch FIRST (stays in flight across compute)
    if (kt + 1 < ntile) {
#pragma unroll
      for (int p = 0; p < 2; ++p) {
        gload_lds16(kp + (((size_t)(b * 1024 + (kt + 1) * 64 + p * 32 + srow)) << 10) + h * 64 + sw * 8,
                    KV[cur ^ 1][0] + tid * 8 + p * 2048);
        gload_lds16(vt + (((size_t)((b * 16 + h) * 64 + p * 32 + srow)) << 10) + (kt + 1) * 64 + sw * 8,
                    KV[cur ^ 1][1] + tid * 8 + p * 2048);
      }
    }
    const u16* Kb = KV[cur][0];
    const u16* Vb = KV[cur][1];

    // QK^T, swapped operands: lane holds S[key=nf*16+lk*4+r][q=l16]
    f32x4 sfr[4] = {};
    __builtin_amdgcn_s_setprio(1);
#pragma unroll
    for (int nf = 0; nf < 4; ++nf) {
      const int krow = nf * 16 + l16;
      bf16x8 bk0 = *(const bf16x8*)(Kb + krow * 64 + (lk ^ e7) * 8);
      bf16x8 bk1 = *(const bf16x8*)(Kb + krow * 64 + ((lk + 4) ^ e7) * 8);
      sfr[nf] = __builtin_amdgcn_mfma_f32_16x16x32_bf16(bk0, aq0, sfr[nf], 0, 0, 0);
      sfr[nf] = __builtin_amdgcn_mfma_f32_16x16x32_bf16(bk1, aq1, sfr[nf], 0, 0, 0);
    }
    __builtin_amdgcn_s_setprio(0);

    // fixed-shift softmax; only the single partial tile needs mask math
    const bool partial = (kt == ntile - 1) && (rem != 0);
    u16* Pw = &Ps[w][0];
#pragma unroll
    for (int nf = 0; nf < 4; ++nf) {
      float pv0 = __builtin_amdgcn_exp2f(sfr[nf][0] * SC2);
      float pv1 = __builtin_amdgcn_exp2f(sfr[nf][1] * SC2);
      float pv2 = __builtin_amdgcn_exp2f(sfr[nf][2] * SC2);
      float pv3 = __builtin_amdgcn_exp2f(sfr[nf][3] * SC2);
      if (partial) {
        const int k0 = nf * 16 + lk * 4;
        pv0 = (k0 + 0 < rem) ? pv0 : 0.f;
        pv1 = (k0 + 1 < rem) ? pv1 : 0.f;
        pv2 = (k0 + 2 < rem) ? pv2 : 0.f;
        pv3 = (k0 + 3 < rem) ? pv3 : 0.f;
      }
      lsumq += (pv0 + pv1) + (pv2 + pv3);
      unsigned lo = (unsigned)f2bf(pv0) | ((unsigned)f2bf(pv1) << 16);
      unsigned hi = (unsigned)f2bf(pv2) | ((unsigned)f2bf(pv3) << 16);
      // chunk (nf*2 + lk>>1) XOR (l16&7), sub-slot lk&1
      *(uint2*)(Pw + l16 * 64 + (((nf * 2 + (lk >> 1)) ^ e7) * 8 + (lk & 1) * 4)) =
          make_uint2(lo, hi);
    }

    bf16x8 ap0 = *(const bf16x8*)(Pw + l16 * 64 + ((lk ^ e7) * 8));
    bf16x8 ap1 = *(const bf16x8*)(Pw + l16 * 64 + (((4 + lk) ^ e7) * 8));
    __builtin_amdgcn_s_setprio(1);
#pragma unroll
    for (int nf = 0; nf < 4; ++nf) {
      const int vrow = nf * 16 + l16;
      bf16x8 bv0 = *(const bf16x8*)(Vb + vrow * 64 + (lk ^ e7) * 8);
      bf16x8 bv1 = *(const bf16x8*)(Vb + vrow * 64 + ((lk + 4) ^ e7) * 8);
      oacc[nf] = __builtin_amdgcn_mfma_f32_16x16x32_bf16(ap0, bv0, oacc[nf], 0, 0, 0);
      oacc[nf] = __builtin_amdgcn_mfma_f32_16x16x32_bf16(ap1, bv1, oacc[nf], 0, 0, 0);
    }
    __builtin_amdgcn_s_setprio(0);

    __syncthreads();  // drains prefetch (vmcnt0) + all waves done with KV[cur]
    cur ^= 1;
  }

  // reduce row-sum across the 4 lanes sharing l16, redistribute to out layout
  lsumq += __shfl_xor(lsumq, 16);
  lsumq += __shfl_xor(lsumq, 32);
  float rinv[4];
#pragma unroll
  for (int r = 0; r < 4; ++r) rinv[r] = 1.0f / __shfl(lsumq, lk * 4 + r);

#pragma unroll
  for (int nf = 0; nf < 4; ++nf)
#pragma unroll
    for (int r = 0; r < 4; ++r) {
      const int tok = b * 1024 + qt * 64 + w * 16 + lk * 4 + r;
      const int col = h * 64 + nf * 16 + l16;
      out[((size_t)tok << 10) + col] = f2bf(oacc[nf][r] * rinv[r]);
    }
}

// ---------------- O-projection GEMM + bias + f32 residual ----------------
// 3-buffer + register-dbuf-frag pipeline (kept from R9: positive at 3
// blocks/CU where TLP covers the reduced DMA slack); 48KB LDS.
__global__ __launch_bounds__(256, 3) void gemm_o(
    const u16* __restrict__ A, const u16* __restrict__ Bt,
    const float* __restrict__ bias, float* __restrict__ Cf,
    const float* __restrict__ res) {
  __shared__ __align__(16) u16 As[3][128 * 32];
  __shared__ __align__(16) u16 Bs[3][128 * 32];
  const int K = 1024, N = 1024, nk = 32;
  const int tid = threadIdx.x;
  const int m0 = blockIdx.x * 128, n0 = blockIdx.y * 128;
  const int lane = tid & 63, w = tid >> 6;
  const int wr = w >> 1, wc = w & 1;
  const int l16 = lane & 15, lk = lane >> 4;
  const int srow = tid >> 2;
  const int sw = (tid & 3) ^ ((tid >> 3) & 3);
  const int e2 = (l16 >> 1) & 3;

  const u16* Ap = A + (size_t)(m0 + srow) * K + sw * 8;
  const u16* Bp = Bt + (size_t)(n0 + srow) * K + sw * 8;

  f32x4 acc[4][4] = {};
  bf16x8 aA[4], bA[4], aB[4], bB[4];

  auto stage = [&](int t, int ktile) {
    const int ko = ktile << 5;
#pragma unroll
    for (int p = 0; p < 2; ++p) {
      gload_lds16(Ap + (size_t)p * 64 * K + ko, As[t] + tid * 8 + p * 2048);
      gload_lds16(Bp + (size_t)p * 64 * K + ko, Bs[t] + tid * 8 + p * 2048);
    }
  };
  auto rd = [&](bf16x8 (&a)[4], bf16x8 (&b)[4], int c) {
#pragma unroll
    for (int i = 0; i < 4; ++i)
      a[i] = *(const bf16x8*)(As[c] + (wr * 64 + i * 16 + l16) * 32 + (lk ^ e2) * 8);
#pragma unroll
    for (int j = 0; j < 4; ++j)
      b[j] = *(const bf16x8*)(Bs[c] + (wc * 64 + j * 16 + l16) * 32 + (lk ^ e2) * 8);
  };
  auto mm = [&](bf16x8 (&a)[4], bf16x8 (&b)[4]) {
    __builtin_amdgcn_s_setprio(1);
#pragma unroll
    for (int i = 0; i < 4; ++i)
#pragma unroll
      for (int j = 0; j < 4; ++j)
        acc[i][j] = __builtin_amdgcn_mfma_f32_16x16x32_bf16(a[i], b[j], acc[i][j], 0, 0, 0);
    __builtin_amdgcn_s_setprio(0);
  };

  stage(0, 0);
  stage(1, 1);
  VMCNT(4);
  barrier_raw();
  rd(aA, bA, 0);
  LGKM0();

  int cur = 0;
  for (int kt = 0; kt < nk; kt += 2) {
    const int c1 = (cur == 2) ? 0 : cur + 1;
    const int c2 = (c1 == 2) ? 0 : c1 + 1;
    if (kt + 2 < nk) { stage(c2, kt + 2); VMCNT(4); }
    else { VMCNT(0); }
    barrier_raw();
    rd(aB, bB, c1);
    mm(aA, bA);
    LGKM0();
    barrier_raw();
    if (kt + 3 < nk) { stage(cur, kt + 3); VMCNT(4); }
    else { VMCNT(0); }
    barrier_raw();
    if (kt + 2 < nk) rd(aA, bA, c2);
    mm(aB, bB);
    LGKM0();
    barrier_raw();
    cur = c2;
  }

#pragma unroll
  for (int i = 0; i < 4; ++i) {
    const int mrow = m0 + wr * 64 + i * 16 + lk * 4;
#pragma unroll
    for (int j = 0; j < 4; ++j) {
      const int col = n0 + wc * 64 + j * 16 + l16;
      const float bval = bias[col];
#pragma unroll
      for (int r = 0; r < 4; ++r) {
        const size_t idx = (size_t)(mrow + r) * N + col;
        Cf[idx] = acc[i][j][r] + bval + res[idx];
      }
    }
  }
}

// ---------------- in-place LayerNorm over rows of 1024 f32 ----------------
__global__ __launch_bounds__(256) void ln_kernel(float* __restrict__ y,
                                                 const float* __restrict__ gamma,
                                                 const float* __restrict__ beta) {
  __shared__ float ssum[4], ssq[4];
  const int tid = threadIdx.x;
  float* yr = y + ((size_t)blockIdx.x << 10);
  float4 v = *((const float4*)yr + tid);
  float s = v.x + v.y + v.z + v.w;
  float q2 = v.x * v.x + v.y * v.y + v.z * v.z + v.w * v.w;
#pragma unroll
  for (int off = 1; off < 64; off <<= 1) {
    s += __shfl_xor(s, off);
    q2 += __shfl_xor(q2, off);
  }
  if ((tid & 63) == 0) { ssum[tid >> 6] = s; ssq[tid >> 6] = q2; }
  __syncthreads();
  s = ssum[0] + ssum[1] + ssum[2] + ssum[3];
  q2 = ssq[0] + ssq[1] + ssq[2] + ssq[3];
  const float mu = s * (1.0f / 1024.0f);
  const float rstd = rsqrtf(q2 * (1.0f / 1024.0f) - mu * mu + 1e-5f);
  float4 g = *((const float4*)gamma + tid);
  float4 be = *((const float4*)beta + tid);
  float4 o;
  o.x = (v.x - mu) * rstd * g.x + be.x;
  o.y = (v.y - mu) * rstd * g.y + be.y;
  o.z = (v.z - mu) * rstd * g.z + be.z;
  o.w = (v.w - mu) * rstd * g.w + be.w;
  *((float4*)yr + tid) = o;
}

extern "C" void kernel_launch(void* const* d_in, const int* in_sizes, int n_in,
                              void* d_out, int out_size, void* d_ws, size_t ws_size,
                              hipStream_t stream) {
  (void)in_sizes; (void)n_in; (void)out_size; (void)ws_size;
  const float* q = (const float*)d_in[0];
  const float* k = (const float*)d_in[1];
  const float* v = (const float*)d_in[2];
  const int* msk = (const int*)d_in[3];
  const float* Wq = (const float*)d_in[4];
  const float* bq = (const float*)d_in[5];
  const float* Wk = (const float*)d_in[6];
  const float* bk = (const float*)d_in[7];
  const float* Wv = (const float*)d_in[8];
  const float* bv = (const float*)d_in[9];
  const float* Wo = (const float*)d_in[10];
  const float* bo = (const float*)d_in[11];
  const float* gamma = (const float*)d_in[12];
  const float* beta = (const float*)d_in[13];
  float* out = (float*)d_out;

  char* p = (char*)d_ws;
  auto take = [&p](size_t bytes) {
    char* r = p;
    p += (bytes + 255) & ~(size_t)255;
    return r;
  };
  u16* qb = (u16*)take(8192ull * 1024 * 2);
  u16* kb = (u16*)take(8192ull * 768 * 2);
  u16* vb = (u16*)take(8192ull * 768 * 2);
  u16* wqb = (u16*)take(1024ull * 1024 * 2);
  u16* wkb = (u16*)take(1024ull * 768 * 2);
  u16* wvb = (u16*)take(1024ull * 768 * 2);
  u16* wob = (u16*)take(1024ull * 1024 * 2);
  u16* qpb = (u16*)take(8192ull * 1024 * 2);
  u16* kpb = (u16*)take(8192ull * 1024 * 2);
  u16* vtb = (u16*)take(8192ull * 1024 * 2);  // [B][H][64][1024]
  u16* atb = (u16*)take(8192ull * 1024 * 2);

  cast_all<<<dim3(24064), 256, 0, stream>>>(q, k, v, Wq, Wk, Wv, Wo, qb);

  proj_kernel<<<dim3(32, 24), 256, 0, stream>>>(qb, kb, vb, wqb, wkb, wvb,
                                                bq, bk, bv, qpb, kpb, vtb);

  attn_kernel<<<dim3(2048), 256, 0, stream>>>(qpb, kpb, vtb, msk, atb);

  gemm_o<<<dim3(64, 8), 256, 0, stream>>>(atb, wob, bo, out, q);

  ln_kernel<<<dim3(8192), 256, 0, stream>>>(out, gamma, beta);
}

// Round 11
// 174.336 us; speedup vs baseline: 1.1595x; 1.0053x over previous
//
#include <hip/hip_runtime.h>
#include <stdint.h>

typedef float f32x4 __attribute__((ext_vector_type(4)));
typedef __bf16 bf16x8 __attribute__((ext_vector_type(8)));
typedef unsigned short u16;

__device__ __forceinline__ void gload_lds16(const void* g, void* l) {
  __builtin_amdgcn_global_load_lds(
      (__attribute__((address_space(1))) void*)(uintptr_t)(g),
      (__attribute__((address_space(3))) void*)(uint32_t)(uintptr_t)(l),
      16, 0, 0);
}

__device__ __forceinline__ u16 f2bf(float x) {
  __bf16 h = (__bf16)x;
  return *(u16*)&h;
}

__device__ __forceinline__ void barrier_raw() {
  __builtin_amdgcn_sched_barrier(0);
  __builtin_amdgcn_s_barrier();
  __builtin_amdgcn_sched_barrier(0);
}

#define VMCNT(n) asm volatile("s_waitcnt vmcnt(" #n ")" ::: "memory")

// ---------------- fused cast f32 -> bf16 for all 7 arrays ----------------
__global__ __launch_bounds__(256) void cast_all(
    const float* __restrict__ q, const float* __restrict__ k,
    const float* __restrict__ v, const float* __restrict__ wq,
    const float* __restrict__ wk, const float* __restrict__ wv,
    const float* __restrict__ wo, u16* __restrict__ out) {
  const int g = blockIdx.x;
  const float* in;
  int s;
  if (g < 8192) { in = q; s = 0; }
  else if (g < 14336) { in = k; s = 8192; }
  else if (g < 20480) { in = v; s = 14336; }
  else if (g < 21504) { in = wq; s = 20480; }
  else if (g < 22272) { in = wk; s = 21504; }
  else if (g < 23040) { in = wv; s = 22272; }
  else { in = wo; s = 23040; }
  const int li = (g - s) * 256 + threadIdx.x;
  float4 x = *((const float4*)in + li);
  unsigned lo = (unsigned)f2bf(x.x) | ((unsigned)f2bf(x.y) << 16);
  unsigned hi = (unsigned)f2bf(x.z) | ((unsigned)f2bf(x.w) << 16);
  ((uint2*)out)[(size_t)g * 256 + threadIdx.x] = make_uint2(lo, hi);
}

// ---------------- merged Q/K/V projection GEMM ----------------
// BM=256 x BN=128, 4 waves (128x64/wave). SINGLE-barrier K-loop, 3 buffers:
//   [vmcnt(6) -> barrier -> stage(kt+2) -> reads(kt) -> MFMA(kt)]
// Correctness: buffer staged at kt was computed at kt-1; each wave's ds_reads
// of it drained before its own MFMA(kt-1) finished, hence before it reached
// barrier(kt); the stage is issued after barrier(kt), so no wave can overwrite
// data still being read. DMA completeness of buf(kt): each wave's vmcnt(6)
// (12 in flight - 6 of tile kt+1) + the barrier. One barrier/step lets waves
// skew a full region -> one wave's MFMA covers another's ds_reads (the two-
// barrier lockstep measured as LDS-phase + MFMA-phase SERIALIZING ~2000cyc).
// Role grouping y>>3 keeps A panels XCD-L2-resident (R8: y%3 = -30%).
__global__ __launch_bounds__(256, 2) void proj_kernel(
    const u16* __restrict__ qb, const u16* __restrict__ kb,
    const u16* __restrict__ vb, const u16* __restrict__ wqb,
    const u16* __restrict__ wkb, const u16* __restrict__ wvb,
    const float* __restrict__ bq, const float* __restrict__ bk,
    const float* __restrict__ bv, u16* __restrict__ qpb,
    u16* __restrict__ kpb, u16* __restrict__ vtb) {
  __shared__ __align__(16) u16 As[3][256 * 32];
  __shared__ __align__(16) u16 Bs[3][128 * 32];
  const int tid = threadIdx.x;
  const int role = blockIdx.y >> 3;
  const int m0 = blockIdx.x * 256, n0 = (blockIdx.y & 7) * 128;
  const int K = (role == 0) ? 1024 : 768;
  const u16* A = (role == 0) ? qb : ((role == 1) ? kb : vb);
  const u16* Bt = (role == 0) ? wqb : ((role == 1) ? wkb : wvb);
  const float* bias = (role == 0) ? bq : ((role == 1) ? bk : bv);
  const int lane = tid & 63, w = tid >> 6;
  const int wr = w >> 1, wc = w & 1;
  const int l16 = lane & 15, lk = lane >> 4;
  const int nk = K >> 5;
  const int srow = tid >> 2;
  const int sw = (tid & 3) ^ ((tid >> 3) & 3);

  const u16* Ap = A + (size_t)(m0 + srow) * K + sw * 8;
  const u16* Bp = Bt + (size_t)(n0 + srow) * K + sw * 8;

  f32x4 acc[8][4] = {};

  auto stage = [&](int t, int ko) {
#pragma unroll
    for (int l = 0; l < 4; ++l)
      gload_lds16(Ap + (size_t)l * 64 * K + ko, As[t] + tid * 8 + l * 2048);
#pragma unroll
    for (int l = 0; l < 2; ++l)
      gload_lds16(Bp + (size_t)l * 64 * K + ko, Bs[t] + tid * 8 + l * 2048);
  };

  // prologue: tiles 0,1 in flight (12 loads)
  stage(0, 0);
  stage(1, 32);

  const int e2 = (l16 >> 1) & 3;  // read-side swizzle
  int cur = 0;
  for (int kt = 0; kt < nk; ++kt) {
    if (kt + 1 < nk) { VMCNT(6); } else { VMCNT(0); }
    barrier_raw();  // buf[cur] fully staged; buf[stg] fully consumed
    if (kt + 2 < nk) {
      const int stg = (cur >= 1) ? cur - 1 : 2;  // (cur+2)%3, computed @ kt-1
      stage(stg, (kt + 2) << 5);
    }
    bf16x8 a[8], b[4];
#pragma unroll
    for (int i = 0; i < 8; ++i)
      a[i] = *(const bf16x8*)(As[cur] + (wr * 128 + i * 16 + l16) * 32 + (lk ^ e2) * 8);
#pragma unroll
    for (int j = 0; j < 4; ++j)
      b[j] = *(const bf16x8*)(Bs[cur] + (wc * 64 + j * 16 + l16) * 32 + (lk ^ e2) * 8);
    __builtin_amdgcn_s_setprio(1);
#pragma unroll
    for (int i = 0; i < 8; ++i)
#pragma unroll
      for (int j = 0; j < 4; ++j)
        acc[i][j] = __builtin_amdgcn_mfma_f32_16x16x32_bf16(a[i], b[j], acc[i][j], 0, 0, 0);
    __builtin_amdgcn_s_setprio(0);
    cur = (cur < 2) ? cur + 1 : 0;
  }

#pragma unroll
  for (int i = 0; i < 8; ++i) {
    const int mrow = m0 + wr * 128 + i * 16 + lk * 4;
#pragma unroll
    for (int j = 0; j < 4; ++j) {
      const int col = n0 + wc * 64 + j * 16 + l16;
      const float bval = bias[col];
      if (role == 0) {
#pragma unroll
        for (int r = 0; r < 4; ++r)
          qpb[(size_t)(mrow + r) * 1024 + col] = f2bf(acc[i][j][r] + bval);
      } else if (role == 1) {
#pragma unroll
        for (int r = 0; r < 4; ++r)
          kpb[(size_t)(mrow + r) * 1024 + col] = f2bf(acc[i][j][r] + bval);
      } else {  // vt[b][h][d][l], rows r are 4 consecutive l
        const int bb = mrow >> 10, l = mrow & 1023;
        const int hh = col >> 6, dd = col & 63;
        u16 u0 = f2bf(acc[i][j][0] + bval);
        u16 u1 = f2bf(acc[i][j][1] + bval);
        u16 u2 = f2bf(acc[i][j][2] + bval);
        u16 u3 = f2bf(acc[i][j][3] + bval);
        uint2 pkt = make_uint2((unsigned)u0 | ((unsigned)u1 << 16),
                               (unsigned)u2 | ((unsigned)u3 << 16));
        *(uint2*)(vtb + ((size_t)((bb * 16 + hh) * 64 + dd) << 10) + l) = pkt;
      }
    }
  }
}

// ---------------- fused masked flash attention ----------------
// grid = 2048 flat, block = 256 (4 waves x 16 q-rows). XCD-locality decode:
// bh = (bid&7) + 8*(bid>>7), qt = (bid>>3)&15 -> all 16 qt-blocks of a (b,h)
// share one XCD; its 256KB K/V panel stays L2-resident.
__global__ __launch_bounds__(256) void attn_kernel(
    const u16* __restrict__ qp, const u16* __restrict__ kp,
    const u16* __restrict__ vt, const int* __restrict__ mask,
    u16* __restrict__ out) {
  __shared__ __align__(16) u16 KV[2][2][64 * 64];  // [buf][0=K,1=V]
  __shared__ __align__(16) u16 Ps[4][16 * 64];     // XOR-swizzled (8-u16 chunks)
  const int tid = threadIdx.x;
  const int bid = blockIdx.x;
  const int qt = (bid >> 3) & 15;
  const int bh = (bid & 7) + ((bid >> 7) << 3);
  const int b = bh >> 4, h = bh & 15;
  const int lane = tid & 63, w = tid >> 6;
  const int l16 = lane & 15, lk = lane >> 4;
  const int srow = tid >> 3, schunk = tid & 7;
  const int sw = schunk ^ (srow & 7);  // pre-swizzled source chunk

  // per-wave prefix-mask popcount -> len (no LDS, no cross-wave comm)
  int cnt = 0;
  {
    const int4* mp = (const int4*)(mask + (b << 10));
#pragma unroll
    for (int i = 0; i < 4; ++i) {
      const int4 mv = mp[lane * 4 + i];
      cnt += (mv.x ? 1 : 0) + (mv.y ? 1 : 0) + (mv.z ? 1 : 0) + (mv.w ? 1 : 0);
    }
#pragma unroll
    for (int off = 1; off < 64; off <<= 1) cnt += __shfl_xor(cnt, off);
  }
  const int ntile = (cnt + 63) >> 6;
  const int rem = cnt & 63;

  // stage Q into KV[1][0] (temporary), K0/V0 into KV[0]
#pragma unroll
  for (int p = 0; p < 2; ++p) {
    gload_lds16(qp + (((size_t)(b * 1024 + qt * 64 + p * 32 + srow)) << 10) + h * 64 + sw * 8,
                KV[1][0] + tid * 8 + p * 2048);
    gload_lds16(kp + (((size_t)(b * 1024 + p * 32 + srow)) << 10) + h * 64 + sw * 8,
                KV[0][0] + tid * 8 + p * 2048);
    gload_lds16(vt + (((size_t)((b * 16 + h) * 64 + p * 32 + srow)) << 10) + sw * 8,
                KV[0][1] + tid * 8 + p * 2048);
  }
  __syncthreads();
  const int qrow = w * 16 + l16, qs = qrow & 7;
  bf16x8 aq0 = *(const bf16x8*)(KV[1][0] + qrow * 64 + (lk ^ qs) * 8);
  bf16x8 aq1 = *(const bf16x8*)(KV[1][0] + qrow * 64 + ((lk + 4) ^ qs) * 8);
  __syncthreads();  // all waves done with Q region before buf1 prefetch

  const float SC2 = 0.18033688011112042f;  // 0.125 * log2(e)
  float lsumq = 0.f;                       // row-sum for q = l16 (per lane)
  f32x4 oacc[4] = {};
  const int e7 = l16 & 7;

  int cur = 0;
  for (int kt = 0; kt < ntile; ++kt) {
    // issue next-tile prefetch FIRST (stays in flight across compute)
    if (kt + 1 < ntile) {
#pragma unroll
      for (int p = 0; p < 2; ++p) {
        gload_lds16(kp + (((size_t)(b * 1024 + (kt + 1) * 64 + p * 32 + srow)) << 10) + h * 64 + sw * 8,
                    KV[cur ^ 1][0] + tid * 8 + p * 2048);
        gload_lds16(vt + (((size_t)((b * 16 + h) * 64 + p * 32 + srow)) << 10) + (kt + 1) * 64 + sw * 8,
                    KV[cur ^ 1][1] + tid * 8 + p * 2048);
      }
    }
    const u16* Kb = KV[cur][0];
    const u16* Vb = KV[cur][1];

    // QK^T, swapped operands: lane holds S[key=nf*16+lk*4+r][q=l16]
    f32x4 sfr[4] = {};
    __builtin_amdgcn_s_setprio(1);
#pragma unroll
    for (int nf = 0; nf < 4; ++nf) {
      const int krow = nf * 16 + l16;
      bf16x8 bk0 = *(const bf16x8*)(Kb + krow * 64 + (lk ^ e7) * 8);
      bf16x8 bk1 = *(const bf16x8*)(Kb + krow * 64 + ((lk + 4) ^ e7) * 8);
      sfr[nf] = __builtin_amdgcn_mfma_f32_16x16x32_bf16(bk0, aq0, sfr[nf], 0, 0, 0);
      sfr[nf] = __builtin_amdgcn_mfma_f32_16x16x32_bf16(bk1, aq1, sfr[nf], 0, 0, 0);
    }
    __builtin_amdgcn_s_setprio(0);

    // fixed-shift softmax; only the single partial tile needs mask math
    const bool partial = (kt == ntile - 1) && (rem != 0);
    u16* Pw = &Ps[w][0];
#pragma unroll
    for (int nf = 0; nf < 4; ++nf) {
      float pv0 = __builtin_amdgcn_exp2f(sfr[nf][0] * SC2);
      float pv1 = __builtin_amdgcn_exp2f(sfr[nf][1] * SC2);
      float pv2 = __builtin_amdgcn_exp2f(sfr[nf][2] * SC2);
      float pv3 = __builtin_amdgcn_exp2f(sfr[nf][3] * SC2);
      if (partial) {
        const int k0 = nf * 16 + lk * 4;
        pv0 = (k0 + 0 < rem) ? pv0 : 0.f;
        pv1 = (k0 + 1 < rem) ? pv1 : 0.f;
        pv2 = (k0 + 2 < rem) ? pv2 : 0.f;
        pv3 = (k0 + 3 < rem) ? pv3 : 0.f;
      }
      lsumq += (pv0 + pv1) + (pv2 + pv3);
      unsigned lo = (unsigned)f2bf(pv0) | ((unsigned)f2bf(pv1) << 16);
      unsigned hi = (unsigned)f2bf(pv2) | ((unsigned)f2bf(pv3) << 16);
      // chunk (nf*2 + lk>>1) XOR (l16&7), sub-slot lk&1
      *(uint2*)(Pw + l16 * 64 + (((nf * 2 + (lk >> 1)) ^ e7) * 8 + (lk & 1) * 4)) =
          make_uint2(lo, hi);
    }

    bf16x8 ap0 = *(const bf16x8*)(Pw + l16 * 64 + ((lk ^ e7) * 8));
    bf16x8 ap1 = *(const bf16x8*)(Pw + l16 * 64 + (((4 + lk) ^ e7) * 8));
    __builtin_amdgcn_s_setprio(1);
#pragma unroll
    for (int nf = 0; nf < 4; ++nf) {
      const int vrow = nf * 16 + l16;
      bf16x8 bv0 = *(const bf16x8*)(Vb + vrow * 64 + (lk ^ e7) * 8);
      bf16x8 bv1 = *(const bf16x8*)(Vb + vrow * 64 + ((lk + 4) ^ e7) * 8);
      oacc[nf] = __builtin_amdgcn_mfma_f32_16x16x32_bf16(ap0, bv0, oacc[nf], 0, 0, 0);
      oacc[nf] = __builtin_amdgcn_mfma_f32_16x16x32_bf16(ap1, bv1, oacc[nf], 0, 0, 0);
    }
    __builtin_amdgcn_s_setprio(0);

    __syncthreads();  // drains prefetch (vmcnt0) + all waves done with KV[cur]
    cur ^= 1;
  }

  // reduce row-sum across the 4 lanes sharing l16, redistribute to out layout
  lsumq += __shfl_xor(lsumq, 16);
  lsumq += __shfl_xor(lsumq, 32);
  float rinv[4];
#pragma unroll
  for (int r = 0; r < 4; ++r) rinv[r] = 1.0f / __shfl(lsumq, lk * 4 + r);

#pragma unroll
  for (int nf = 0; nf < 4; ++nf)
#pragma unroll
    for (int r = 0; r < 4; ++r) {
      const int tok = b * 1024 + qt * 64 + w * 16 + lk * 4 + r;
      const int col = h * 64 + nf * 16 + l16;
      out[((size_t)tok << 10) + col] = f2bf(oacc[nf][r] * rinv[r]);
    }
}

// ---------------- O-projection GEMM + bias + f32 residual ----------------
// Same single-barrier 3-buffer K-loop as proj (vmcnt slack = 4);
// 48KB LDS -> 3 blocks/CU.
__global__ __launch_bounds__(256, 3) void gemm_o(
    const u16* __restrict__ A, const u16* __restrict__ Bt,
    const float* __restrict__ bias, float* __restrict__ Cf,
    const float* __restrict__ res) {
  __shared__ __align__(16) u16 As[3][128 * 32];
  __shared__ __align__(16) u16 Bs[3][128 * 32];
  const int K = 1024, N = 1024, nk = 32;
  const int tid = threadIdx.x;
  const int m0 = blockIdx.x * 128, n0 = blockIdx.y * 128;
  const int lane = tid & 63, w = tid >> 6;
  const int wr = w >> 1, wc = w & 1;
  const int l16 = lane & 15, lk = lane >> 4;
  const int srow = tid >> 2;
  const int sw = (tid & 3) ^ ((tid >> 3) & 3);
  const int e2 = (l16 >> 1) & 3;

  const u16* Ap = A + (size_t)(m0 + srow) * K + sw * 8;
  const u16* Bp = Bt + (size_t)(n0 + srow) * K + sw * 8;

  f32x4 acc[4][4] = {};

  auto stage = [&](int t, int ko) {
#pragma unroll
    for (int p = 0; p < 2; ++p) {
      gload_lds16(Ap + (size_t)p * 64 * K + ko, As[t] + tid * 8 + p * 2048);
      gload_lds16(Bp + (size_t)p * 64 * K + ko, Bs[t] + tid * 8 + p * 2048);
    }
  };

  stage(0, 0);
  stage(1, 32);

  int cur = 0;
  for (int kt = 0; kt < nk; ++kt) {
    if (kt + 1 < nk) { VMCNT(4); } else { VMCNT(0); }
    barrier_raw();
    if (kt + 2 < nk) {
      const int stg = (cur >= 1) ? cur - 1 : 2;
      stage(stg, (kt + 2) << 5);
    }
    bf16x8 a[4], b[4];
#pragma unroll
    for (int i = 0; i < 4; ++i)
      a[i] = *(const bf16x8*)(As[cur] + (wr * 64 + i * 16 + l16) * 32 + (lk ^ e2) * 8);
#pragma unroll
    for (int j = 0; j < 4; ++j)
      b[j] = *(const bf16x8*)(Bs[cur] + (wc * 64 + j * 16 + l16) * 32 + (lk ^ e2) * 8);
    __builtin_amdgcn_s_setprio(1);
#pragma unroll
    for (int i = 0; i < 4; ++i)
#pragma unroll
      for (int j = 0; j < 4; ++j)
        acc[i][j] = __builtin_amdgcn_mfma_f32_16x16x32_bf16(a[i], b[j], acc[i][j], 0, 0, 0);
    __builtin_amdgcn_s_setprio(0);
    cur = (cur < 2) ? cur + 1 : 0;
  }

#pragma unroll
  for (int i = 0; i < 4; ++i) {
    const int mrow = m0 + wr * 64 + i * 16 + lk * 4;
#pragma unroll
    for (int j = 0; j < 4; ++j) {
      const int col = n0 + wc * 64 + j * 16 + l16;
      const float bval = bias[col];
#pragma unroll
      for (int r = 0; r < 4; ++r) {
        const size_t idx = (size_t)(mrow + r) * N + col;
        Cf[idx] = acc[i][j][r] + bval + res[idx];
      }
    }
  }
}

// ---------------- in-place LayerNorm over rows of 1024 f32 ----------------
__global__ __launch_bounds__(256) void ln_kernel(float* __restrict__ y,
                                                 const float* __restrict__ gamma,
                                                 const float* __restrict__ beta) {
  __shared__ float ssum[4], ssq[4];
  const int tid = threadIdx.x;
  float* yr = y + ((size_t)blockIdx.x << 10);
  float4 v = *((const float4*)yr + tid);
  float s = v.x + v.y + v.z + v.w;
  float q2 = v.x * v.x + v.y * v.y + v.z * v.z + v.w * v.w;
#pragma unroll
  for (int off = 1; off < 64; off <<= 1) {
    s += __shfl_xor(s, off);
    q2 += __shfl_xor(q2, off);
  }
  if ((tid & 63) == 0) { ssum[tid >> 6] = s; ssq[tid >> 6] = q2; }
  __syncthreads();
  s = ssum[0] + ssum[1] + ssum[2] + ssum[3];
  q2 = ssq[0] + ssq[1] + ssq[2] + ssq[3];
  const float mu = s * (1.0f / 1024.0f);
  const float rstd = rsqrtf(q2 * (1.0f / 1024.0f) - mu * mu + 1e-5f);
  float4 g = *((const float4*)gamma + tid);
  float4 be = *((const float4*)beta + tid);
  float4 o;
  o.x = (v.x - mu) * rstd * g.x + be.x;
  o.y = (v.y - mu) * rstd * g.y + be.y;
  o.z = (v.z - mu) * rstd * g.z + be.z;
  o.w = (v.w - mu) * rstd * g.w + be.w;
  *((float4*)yr + tid) = o;
}

extern "C" void kernel_launch(void* const* d_in, const int* in_sizes, int n_in,
                              void* d_out, int out_size, void* d_ws, size_t ws_size,
                              hipStream_t stream) {
  (void)in_sizes; (void)n_in; (void)out_size; (void)ws_size;
  const float* q = (const float*)d_in[0];
  const float* k = (const float*)d_in[1];
  const float* v = (const float*)d_in[2];
  const int* msk = (const int*)d_in[3];
  const float* Wq = (const float*)d_in[4];
  const float* bq = (const float*)d_in[5];
  const float* Wk = (const float*)d_in[6];
  const float* bk = (const float*)d_in[7];
  const float* Wv = (const float*)d_in[8];
  const float* bv = (const float*)d_in[9];
  const float* Wo = (const float*)d_in[10];
  const float* bo = (const float*)d_in[11];
  const float* gamma = (const float*)d_in[12];
  const float* beta = (const float*)d_in[13];
  float* out = (float*)d_out;

  char* p = (char*)d_ws;
  auto take = [&p](size_t bytes) {
    char* r = p;
    p += (bytes + 255) & ~(size_t)255;
    return r;
  };
  u16* qb = (u16*)take(8192ull * 1024 * 2);
  u16* kb = (u16*)take(8192ull * 768 * 2);
  u16* vb = (u16*)take(8192ull * 768 * 2);
  u16* wqb = (u16*)take(1024ull * 1024 * 2);
  u16* wkb = (u16*)take(1024ull * 768 * 2);
  u16* wvb = (u16*)take(1024ull * 768 * 2);
  u16* wob = (u16*)take(1024ull * 1024 * 2);
  u16* qpb = (u16*)take(8192ull * 1024 * 2);
  u16* kpb = (u16*)take(8192ull * 1024 * 2);
  u16* vtb = (u16*)take(8192ull * 1024 * 2);  // [B][H][64][1024]
  u16* atb = (u16*)take(8192ull * 1024 * 2);

  cast_all<<<dim3(24064), 256, 0, stream>>>(q, k, v, Wq, Wk, Wv, Wo, qb);

  proj_kernel<<<dim3(32, 24), 256, 0, stream>>>(qb, kb, vb, wqb, wkb, wvb,
                                                bq, bk, bv, qpb, kpb, vtb);

  attn_kernel<<<dim3(2048), 256, 0, stream>>>(qpb, kpb, vtb, msk, atb);

  gemm_o<<<dim3(64, 8), 256, 0, stream>>>(atb, wob, bo, out, q);

  ln_kernel<<<dim3(8192), 256, 0, stream>>>(out, gamma, beta);
}